// Round 10
// baseline (105.725 us; speedup 1.0000x reference)
//
#include <hip/hip_runtime.h>
#include <math.h>

#define NFFT 4096
#define LSEG 2048   // L
#define SSZ 4096    // STATE_SIZE

typedef float v2f __attribute__((ext_vector_type(2)));
typedef float v4f __attribute__((ext_vector_type(4)));

// componentwise fma: identical rounding to R9's scalar fmaf per batch lane
static __device__ __forceinline__ v2f vfma(v2f a, v2f b, v2f c) {
    return (v2f){fmaf(a.x, b.x, c.x), fmaf(a.y, b.y, c.y)};
}

// out = irfft(rfft(s) * H)[-L:] with 2nd-order rational H(z), z = e^{-i theta}
// == CIRCULAR biquad, run causally on the REVERSED signal s'[m] = s[4095-m].
// Partial fractions (poles l1,l2 real, distinct, in (0,1)):
//   y' = c0 s' + c1 w1 + c2 w2,   wi = li*wi + s'   (weighted prefix scan)
// Circular wrap folded into the scan seed: w_c[m0-1] = W[m0-1] + li^{m0} * K,
//   K = W_total / (1 - li^4096).
// R10: one block per PAIR of batches -- batch a in .x, batch b in .y of every
// packed v2f. Halves the grid to 1024 blocks (= 4/CU, single residency round).
__global__ __launch_bounds__(256, 4)
void preamp_iir_kernel(const float* __restrict__ x,
                       const float* __restrict__ state,
                       const float* __restrict__ cond,
                       const float* __restrict__ a_rg,
                       const float* __restrict__ a_r1,
                       const float* __restrict__ a_c1,
                       const float* __restrict__ a_c2,
                       const float* __restrict__ cond_w,
                       const float* __restrict__ cond_b,
                       float* __restrict__ out, int B) {
    __shared__ float cf[26];     // 13 coefs x {batch a, batch b} interleaved
    __shared__ v2f Tw[2][4];     // per-wave scan totals, per pole (packed)

    const int t = threadIdx.x;
    const int b0 = 2 * blockIdx.x;
    const int b1 = (b0 + 1 < B) ? b0 + 1 : b0;
    const int lane = t & 63;
    const int wv = t >> 6;

    const float* xa  = x + (size_t)b0 * LSEG;
    const float* sta = state + (size_t)b0 * SSZ + (SSZ - LSEG);
    const float* xbp = x + (size_t)b1 * LSEG;
    const float* stb = state + (size_t)b1 * SSZ + (SSZ - LSEG);

    // ---- reversed load: s[j] = buf[4095 - (16t + j)], buf = [state_tail, x] ----
    v2f s[16];
    if (t < 128) {
#pragma unroll
        for (int u = 0; u < 4; ++u) {
            const int g0 = 4092 - 16 * t - 4 * u;      // >= 2048
            v4f va = *(const v4f*)(xa + (g0 - LSEG));
            v4f vb = *(const v4f*)(xbp + (g0 - LSEG));
            s[4 * u + 0] = (v2f){va.w, vb.w}; s[4 * u + 1] = (v2f){va.z, vb.z};
            s[4 * u + 2] = (v2f){va.y, vb.y}; s[4 * u + 3] = (v2f){va.x, vb.x};
        }
    } else {
#pragma unroll
        for (int u = 0; u < 4; ++u) {
            const int g0 = 4092 - 16 * t - 4 * u;      // in [0, 2044]
            v4f va = *(const v4f*)(sta + g0);
            v4f vb = *(const v4f*)(stb + g0);
            s[4 * u + 0] = (v2f){va.w, vb.w}; s[4 * u + 1] = (v2f){va.z, vb.z};
            s[4 * u + 2] = (v2f){va.y, vb.y}; s[4 * u + 3] = (v2f){va.x, vb.x};
        }
    }

    // ---- coefficient computation (threads 0 and 128, fp64 DK-method algebra) ----
    if ((t & 127) == 0) {
        const int who = t >> 7;
        const int bb = who ? b1 : b0;

        const double RG = (0.9 + (double)(1.0f / (1.0f + expf(-a_rg[0]))) * 0.2) * 1.0e6;
        const double R1 = (0.99 + (double)(1.0f / (1.0f + expf(-a_r1[0]))) * 0.02) * 4.7e5;
        const double C1 = (0.9 + (double)(1.0f / (1.0f + expf(-a_c1[0]))) * 0.2) * 3.3e-9;
        const double C2 = (0.9 + (double)(1.0f / (1.0f + expf(-a_c2[0]))) * 0.2) * 1.0e-9;
        const double g1 = 1.0 / R1;
        const double gc1 = 2.0 * C1 * 44100.0;
        const double gc2 = 2.0 * C2 * 44100.0;

        float zf = cond[bb] * cond_w[0] + cond_b[0];
        float pot = 1.0f / (1.0f + expf(-zf));
        float prf = (powf(10.0f, pot) - 1.0f) / 9.0f;
        prf = fminf(fmaxf(prf, 1e-4f), 1.0f - 1e-4f);
        const double p = (double)prf;

        // Analytic So^{-1}
        const double ds = gc1 + g1;
        double S[4][4] = {
            {0.0, 0.0,        0.0,       1.0},
            {0.0, 1.0 / ds,   0.0,       gc1 / ds},
            {0.0, 0.0,        1.0 / gc2, 0.0},
            {1.0, gc1 / ds,   0.0,       -gc1 * g1 / ds}};

        double Q00 = S[1][1] - S[1][2] - S[2][1] + S[2][2];
        double Q01 = S[1][2] - S[2][2];
        double Q10 = S[2][1] - S[2][2];
        double Q11 = S[2][2];

        double Ux00 = S[0][1] - S[0][2] - S[1][1] + S[1][2];
        double Ux01 = S[0][2] - S[1][2];
        double Ux10 = S[2][1] - S[2][2];
        double Ux11 = S[2][2];

        double Uo0 = S[2][1] - S[2][2], Uo1 = S[2][2];
        double Uu0 = S[3][1] - S[3][2], Uu1 = S[3][2];

        double P00 = S[0][0] - S[0][1] - S[1][0] + S[1][1];
        double P01 = S[0][2] - S[1][2];
        double P10 = S[2][0] - S[2][1];
        double P11 = S[2][2];

        double Ao00 = 2.0 * gc1 * P00 - 1.0, Ao01 = 2.0 * gc1 * P01;
        double Ao10 = 2.0 * gc2 * P10,       Ao11 = 2.0 * gc2 * P11 - 1.0;

        double Bo0 = 2.0 * gc1 * (S[0][3] - S[1][3]);
        double Bo1 = 2.0 * gc2 * S[2][3];

        double Do0 = S[2][0] - S[2][1], Do1 = S[2][2];
        double Eo  = S[2][3];

        double T00 = 2.0 * gc1 * Ux00, T01 = 2.0 * gc1 * Ux01;
        double T10 = 2.0 * gc2 * Ux10, T11 = 2.0 * gc2 * Ux11;

        double d0 = (1.0 - p) * RG, d1v = p * RG;
        double M00 = d0 + Q00, M01 = Q01, M10 = Q10, M11 = d1v + Q11;
        double idet = 1.0 / (M00 * M11 - M01 * M10);
        double G00 =  M11 * idet, G01 = -M01 * idet;
        double G10 = -M10 * idet, G11 =  M00 * idet;

        double TG00 = T00 * G00 + T01 * G10, TG01 = T00 * G01 + T01 * G11;
        double TG10 = T10 * G00 + T11 * G10, TG11 = T10 * G01 + T11 * G11;

        double A00 = Ao00 - (TG00 * Ux00 + TG01 * Ux01);
        double A01 = Ao01 - (TG00 * Ux10 + TG01 * Ux11);
        double A10 = Ao10 - (TG10 * Ux00 + TG11 * Ux01);
        double A11 = Ao11 - (TG10 * Ux10 + TG11 * Ux11);

        double Bm0 = Bo0 - (TG00 * Uu0 + TG01 * Uu1);
        double Bm1 = Bo1 - (TG10 * Uu0 + TG11 * Uu1);

        double w0v = Uo0 * G00 + Uo1 * G10, w1v = Uo0 * G01 + Uo1 * G11;
        double Dm0 = Do0 - (w0v * Ux00 + w1v * Ux01);
        double Dm1 = Do1 - (w0v * Ux10 + w1v * Ux11);
        double Em  = Eo  - (w0v * Uu0 + w1v * Uu1);

        double den1 = -(A00 + A11);
        double den2 = A00 * A11 - A01 * A10;
        double Mm00 = A00 - Bm0 * Dm0, Mm01 = A01 - Bm0 * Dm1;
        double Mm10 = A10 - Bm1 * Dm0, Mm11 = A11 - Bm1 * Dm1;
        double num0 = Em;
        double num1 = -(Mm00 + Mm11) + (Em - 1.0) * den1;
        double num2 = (Mm00 * Mm11 - Mm01 * Mm10) + (Em - 1.0) * den2;

        // ---- poles (eigenvalues of A; real & distinct for this RC ladder) ----
        double trA  = A00 + A11;                  // = -den1
        double disc = den1 * den1 - 4.0 * den2;
        double sq   = sqrt(disc > 0.0 ? disc : 0.0);
        double L1d  = 0.5 * (trA + sq);
        double L2d  = 0.5 * (trA - sq);
        // partial-fraction residues
        double nv1 = (num0 * L1d + num1) * L1d + num2;   // num(L1)
        double nv2 = (num0 * L2d + num1) * L2d + num2;   // num(L2)
        double C0d =  num2 / den2;
        double C1d =  nv1 / (L1d * sq);
        double C2d = -nv2 / (L2d * sq);
        // pole powers for the scan / circular correction
        double a2 = L1d * L1d, a4 = a2 * a2, a8 = a4 * a4, F16a = a8 * a8;
        double a32 = F16a * F16a, a64 = a32 * a32, a128 = a64 * a64,
               a256 = a128 * a128, a512 = a256 * a256, F1ka = a512 * a512;
        double F4ka = (F1ka * F1ka) * (F1ka * F1ka);
        double b2 = L2d * L2d, b4 = b2 * b2, b8 = b4 * b4, F16b = b8 * b8;
        double b32 = F16b * F16b, b64 = b32 * b32, b128 = b64 * b64,
               b256 = b128 * b128, b512 = b256 * b256, F1kb = b512 * b512;
        double F4kb = (F1kb * F1kb) * (F1kb * F1kb);

        cf[0  + who] = (float)L1d;
        cf[2  + who] = (float)L2d;
        cf[4  + who] = (float)C0d;
        cf[6  + who] = (float)C1d;
        cf[8  + who] = (float)C2d;
        cf[10 + who] = (float)F16a;
        cf[12 + who] = (float)F16b;
        cf[14 + who] = 16.0f * log2f((float)L1d);
        cf[16 + who] = 16.0f * log2f((float)L2d);
        cf[18 + who] = (float)F1ka;
        cf[20 + who] = (float)F1kb;
        cf[22 + who] = (float)(1.0 / (1.0 - F4ka));
        cf[24 + who] = (float)(1.0 / (1.0 - F4kb));
    }
    __syncthreads();

    const v2f lam1 = {cf[0],  cf[1]},  lam2 = {cf[2],  cf[3]};
    const v2f c0   = {cf[4],  cf[5]},  c1   = {cf[6],  cf[7]},  c2 = {cf[8], cf[9]};
    const v2f f16a = {cf[10], cf[11]}, f16b = {cf[12], cf[13]};
    const v2f l2a  = {cf[14], cf[15]}, l2b  = {cf[16], cf[17]};
    const v2f f1ka = {cf[18], cf[19]}, f1kb = {cf[20], cf[21]};
    const v2f ioma = {cf[22], cf[23]}, iomb = {cf[24], cf[25]};

    // ---- local partials: r_t = sum_j lam^{15-j} s[j] (both poles, both batches) ----
    v2f w1 = {0.0f, 0.0f}, w2 = {0.0f, 0.0f};
#pragma unroll
    for (int j = 0; j < 16; ++j) {
        w1 = vfma(lam1, w1, s[j]);
        w2 = vfma(lam2, w2, s[j]);
    }

    // ---- intra-wave weighted inclusive scan (combine factor lam^16) ----
    v2f f1 = f16a, f2 = f16b;
#pragma unroll
    for (int d = 1; d < 64; d <<= 1) {
        v2f o1 = {__shfl_up(w1.x, d), __shfl_up(w1.y, d)};
        v2f o2 = {__shfl_up(w2.x, d), __shfl_up(w2.y, d)};
        if (lane >= d) { w1 = vfma(f1, o1, w1); w2 = vfma(f2, o2, w2); }
        f1 = (v2f){f1.x * f1.x, f1.y * f1.y};
        f2 = (v2f){f2.x * f2.x, f2.y * f2.y};
    }
    if (lane == 63) { Tw[0][wv] = w1; Tw[1][wv] = w2; }
    __syncthreads();

    // ---- emit: only waves 0,1 (reversed positions m = 16t..16t+15 -> out[2047-m]) ----
    if (t < 128) {
        // cross-wave prefix (wave 0: none; wave 1: wave 0's total)
        v2f S1 = {0.0f, 0.0f}, S2 = {0.0f, 0.0f};
        if (wv == 1) { S1 = Tw[0][0]; S2 = Tw[1][0]; }
        const v2f el1 = {exp2f((float)lane * l2a.x), exp2f((float)lane * l2a.y)};
        const v2f el2 = {exp2f((float)lane * l2b.x), exp2f((float)lane * l2b.y)};
        // merged inclusive value, then incoming prefix W[m0-1]
        w1 = vfma((v2f){el1.x * f16a.x, el1.y * f16a.y}, S1, w1);
        w2 = vfma((v2f){el2.x * f16b.x, el2.y * f16b.y}, S2, w2);
        v2f p1 = {__shfl_up(w1.x, 1), __shfl_up(w1.y, 1)};
        v2f p2 = {__shfl_up(w2.x, 1), __shfl_up(w2.y, 1)};
        if (lane == 0) { p1 = S1; p2 = S2; }

        // block totals (= W[4095]) from the 4 wave totals; periodic K
        v2f K1 = vfma(vfma(vfma(Tw[0][0], f1ka, Tw[0][1]), f1ka, Tw[0][2]), f1ka, Tw[0][3]);
        v2f K2 = vfma(vfma(vfma(Tw[1][0], f1kb, Tw[1][1]), f1kb, Tw[1][2]), f1kb, Tw[1][3]);
        K1 = (v2f){K1.x * ioma.x, K1.y * ioma.y};
        K2 = (v2f){K2.x * iomb.x, K2.y * iomb.y};

        // seed the replay with the periodic correction: w_c[m0-1] = p + lam^{16t} * K
        const v2f one = {1.0f, 1.0f};
        const v2f pf1 = wv ? f1ka : one;
        const v2f pf2 = wv ? f1kb : one;
        v2f w1r = vfma((v2f){el1.x * pf1.x, el1.y * pf1.y}, K1, p1);
        v2f w2r = vfma((v2f){el2.x * pf2.x, el2.y * pf2.y}, K2, p2);

        float* oa = out + (size_t)b0 * LSEG;
        float* ob = out + (size_t)b1 * LSEG;
#pragma unroll
        for (int u = 0; u < 4; ++u) {
            v2f y0, y1, y2, y3;
            {
                const v2f sv = s[4 * u + 0];
                w1r = vfma(lam1, w1r, sv); w2r = vfma(lam2, w2r, sv);
                y0 = vfma(c0, sv, vfma(c2, w2r, (v2f){c1.x * w1r.x, c1.y * w1r.y}));
            }
            {
                const v2f sv = s[4 * u + 1];
                w1r = vfma(lam1, w1r, sv); w2r = vfma(lam2, w2r, sv);
                y1 = vfma(c0, sv, vfma(c2, w2r, (v2f){c1.x * w1r.x, c1.y * w1r.y}));
            }
            {
                const v2f sv = s[4 * u + 2];
                w1r = vfma(lam1, w1r, sv); w2r = vfma(lam2, w2r, sv);
                y2 = vfma(c0, sv, vfma(c2, w2r, (v2f){c1.x * w1r.x, c1.y * w1r.y}));
            }
            {
                const v2f sv = s[4 * u + 3];
                w1r = vfma(lam1, w1r, sv); w2r = vfma(lam2, w2r, sv);
                y3 = vfma(c0, sv, vfma(c2, w2r, (v2f){c1.x * w1r.x, c1.y * w1r.y}));
            }
            const int o0 = 2044 - 16 * t - 4 * u;
            v4f oA; oA.x = y3.x; oA.y = y2.x; oA.z = y1.x; oA.w = y0.x;
            *(v4f*)(oa + o0) = oA;
            v4f oB; oB.x = y3.y; oB.y = y2.y; oB.z = y1.y; oB.w = y0.y;
            *(v4f*)(ob + o0) = oB;
        }
    }
}

extern "C" void kernel_launch(void* const* d_in, const int* in_sizes, int n_in,
                              void* d_out, int out_size, void* d_ws, size_t ws_size,
                              hipStream_t stream) {
    const float* x     = (const float*)d_in[0];
    const float* cond  = (const float*)d_in[1];
    const float* state = (const float*)d_in[2];
    const float* a_rg  = (const float*)d_in[3];
    const float* a_r1  = (const float*)d_in[4];
    const float* a_c1  = (const float*)d_in[5];
    const float* a_c2  = (const float*)d_in[6];
    const float* c_w   = (const float*)d_in[7];
    const float* c_b   = (const float*)d_in[8];
    float* out = (float*)d_out;

    const int B = in_sizes[1];          // cond is [B,1]

    preamp_iir_kernel<<<dim3((B + 1) / 2), dim3(256), 0, stream>>>(
        x, state, cond, a_rg, a_r1, a_c1, a_c2, c_w, c_b, out, B);
}

// Round 11
// 104.889 us; speedup vs baseline: 1.0080x; 1.0080x over previous
//
#include <hip/hip_runtime.h>
#include <math.h>

#define NFFT 4096
#define LSEG 2048   // L
#define SSZ 4096    // STATE_SIZE

typedef float v4f __attribute__((ext_vector_type(4)));

// out = irfft(rfft(s) * H)[-L:] with 2nd-order rational H(z), z = e^{-i theta}
// == CIRCULAR biquad, run causally on the REVERSED signal s'[m] = s[4095-m].
// Partial fractions (poles l1,l2 real, distinct, in (0,1)):
//   y' = c0 s' + c1 w1 + c2 w2,   wi = li*wi + s'   (weighted prefix scan)
// Circular wrap folded into the scan seed: w_c[m0-1] = W[m0-1] + li^{m0} * K,
//   K = W_total / (1 - li^4096)  -- the recurrence then propagates li^{m+1}K.
// Output needs only m in [0,2048) of the reversed stream (threads 0..127).
__global__ __launch_bounds__(256, 4)
void preamp_iir_kernel(const float* __restrict__ x,
                       const float* __restrict__ state,
                       const float* __restrict__ cond,
                       const float* __restrict__ a_rg,
                       const float* __restrict__ a_r1,
                       const float* __restrict__ a_c1,
                       const float* __restrict__ a_c2,
                       const float* __restrict__ cond_w,
                       const float* __restrict__ cond_b,
                       float* __restrict__ out, int B) {
    __shared__ float cf[13];     // lam1,lam2,c0,c1,c2,f16a,f16b,l2a,l2b,f1ka,f1kb,ioma,iomb
    __shared__ float Tw[2][4];   // per-wave scan totals, per pole

    const int t = threadIdx.x;
    const int b = blockIdx.x;
    const int lane = t & 63;
    const int wv = t >> 6;

    const float* xb  = x + (size_t)b * LSEG;
    const float* stb = state + (size_t)b * SSZ + (SSZ - LSEG);

    // ---- reversed load: s[j] = buf[4095 - (16t + j)], buf = [state_tail, x] ----
    float s[16];
    if (t < 128) {
#pragma unroll
        for (int u = 0; u < 4; ++u) {
            const int g0 = 4092 - 16 * t - 4 * u;      // >= 2048
            v4f v = *(const v4f*)(xb + (g0 - LSEG));
            s[4 * u + 0] = v.w; s[4 * u + 1] = v.z;
            s[4 * u + 2] = v.y; s[4 * u + 3] = v.x;
        }
    } else {
#pragma unroll
        for (int u = 0; u < 4; ++u) {
            const int g0 = 4092 - 16 * t - 4 * u;      // in [0, 2044]
            v4f v = *(const v4f*)(stb + g0);
            s[4 * u + 0] = v.w; s[4 * u + 1] = v.z;
            s[4 * u + 2] = v.y; s[4 * u + 3] = v.x;
        }
    }

    // ---- coefficient computation (thread 0, fp64 DK-method algebra) ----
    if (t == 0) {
        const double RG = (0.9 + (double)(1.0f / (1.0f + expf(-a_rg[0]))) * 0.2) * 1.0e6;
        const double R1 = (0.99 + (double)(1.0f / (1.0f + expf(-a_r1[0]))) * 0.02) * 4.7e5;
        const double C1 = (0.9 + (double)(1.0f / (1.0f + expf(-a_c1[0]))) * 0.2) * 3.3e-9;
        const double C2 = (0.9 + (double)(1.0f / (1.0f + expf(-a_c2[0]))) * 0.2) * 1.0e-9;
        const double g1 = 1.0 / R1;
        const double gc1 = 2.0 * C1 * 44100.0;
        const double gc2 = 2.0 * C2 * 44100.0;

        float zf = cond[b] * cond_w[0] + cond_b[0];
        float pot = 1.0f / (1.0f + expf(-zf));
        float prf = (powf(10.0f, pot) - 1.0f) / 9.0f;
        prf = fminf(fmaxf(prf, 1e-4f), 1.0f - 1e-4f);
        const double p = (double)prf;

        // Analytic So^{-1}
        const double ds = gc1 + g1;
        double S[4][4] = {
            {0.0, 0.0,        0.0,       1.0},
            {0.0, 1.0 / ds,   0.0,       gc1 / ds},
            {0.0, 0.0,        1.0 / gc2, 0.0},
            {1.0, gc1 / ds,   0.0,       -gc1 * g1 / ds}};

        double Q00 = S[1][1] - S[1][2] - S[2][1] + S[2][2];
        double Q01 = S[1][2] - S[2][2];
        double Q10 = S[2][1] - S[2][2];
        double Q11 = S[2][2];

        double Ux00 = S[0][1] - S[0][2] - S[1][1] + S[1][2];
        double Ux01 = S[0][2] - S[1][2];
        double Ux10 = S[2][1] - S[2][2];
        double Ux11 = S[2][2];

        double Uo0 = S[2][1] - S[2][2], Uo1 = S[2][2];
        double Uu0 = S[3][1] - S[3][2], Uu1 = S[3][2];

        double P00 = S[0][0] - S[0][1] - S[1][0] + S[1][1];
        double P01 = S[0][2] - S[1][2];
        double P10 = S[2][0] - S[2][1];
        double P11 = S[2][2];

        double Ao00 = 2.0 * gc1 * P00 - 1.0, Ao01 = 2.0 * gc1 * P01;
        double Ao10 = 2.0 * gc2 * P10,       Ao11 = 2.0 * gc2 * P11 - 1.0;

        double Bo0 = 2.0 * gc1 * (S[0][3] - S[1][3]);
        double Bo1 = 2.0 * gc2 * S[2][3];

        double Do0 = S[2][0] - S[2][1], Do1 = S[2][2];
        double Eo  = S[2][3];

        double T00 = 2.0 * gc1 * Ux00, T01 = 2.0 * gc1 * Ux01;
        double T10 = 2.0 * gc2 * Ux10, T11 = 2.0 * gc2 * Ux11;

        double d0 = (1.0 - p) * RG, d1v = p * RG;
        double M00 = d0 + Q00, M01 = Q01, M10 = Q10, M11 = d1v + Q11;
        double idet = 1.0 / (M00 * M11 - M01 * M10);
        double G00 =  M11 * idet, G01 = -M01 * idet;
        double G10 = -M10 * idet, G11 =  M00 * idet;

        double TG00 = T00 * G00 + T01 * G10, TG01 = T00 * G01 + T01 * G11;
        double TG10 = T10 * G00 + T11 * G10, TG11 = T10 * G01 + T11 * G11;

        double A00 = Ao00 - (TG00 * Ux00 + TG01 * Ux01);
        double A01 = Ao01 - (TG00 * Ux10 + TG01 * Ux11);
        double A10 = Ao10 - (TG10 * Ux00 + TG11 * Ux01);
        double A11 = Ao11 - (TG10 * Ux10 + TG11 * Ux11);

        double Bm0 = Bo0 - (TG00 * Uu0 + TG01 * Uu1);
        double Bm1 = Bo1 - (TG10 * Uu0 + TG11 * Uu1);

        double w0v = Uo0 * G00 + Uo1 * G10, w1v = Uo0 * G01 + Uo1 * G11;
        double Dm0 = Do0 - (w0v * Ux00 + w1v * Ux01);
        double Dm1 = Do1 - (w0v * Ux10 + w1v * Ux11);
        double Em  = Eo  - (w0v * Uu0 + w1v * Uu1);

        double den1 = -(A00 + A11);
        double den2 = A00 * A11 - A01 * A10;
        double Mm00 = A00 - Bm0 * Dm0, Mm01 = A01 - Bm0 * Dm1;
        double Mm10 = A10 - Bm1 * Dm0, Mm11 = A11 - Bm1 * Dm1;
        double num0 = Em;
        double num1 = -(Mm00 + Mm11) + (Em - 1.0) * den1;
        double num2 = (Mm00 * Mm11 - Mm01 * Mm10) + (Em - 1.0) * den2;

        // ---- poles (eigenvalues of A; real & distinct for this RC ladder) ----
        double trA  = A00 + A11;                  // = -den1
        double disc = den1 * den1 - 4.0 * den2;
        double sq   = sqrt(disc > 0.0 ? disc : 0.0);
        double L1d  = 0.5 * (trA + sq);
        double L2d  = 0.5 * (trA - sq);
        // partial-fraction residues
        double nv1 = (num0 * L1d + num1) * L1d + num2;   // num(L1)
        double nv2 = (num0 * L2d + num1) * L2d + num2;   // num(L2)
        double C0d =  num2 / den2;
        double C1d =  nv1 / (L1d * sq);
        double C2d = -nv2 / (L2d * sq);
        // pole powers for the scan / circular correction
        double a2 = L1d * L1d, a4 = a2 * a2, a8 = a4 * a4, F16a = a8 * a8;
        double a32 = F16a * F16a, a64 = a32 * a32, a128 = a64 * a64,
               a256 = a128 * a128, a512 = a256 * a256, F1ka = a512 * a512;
        double F4ka = (F1ka * F1ka) * (F1ka * F1ka);
        double b2 = L2d * L2d, b4 = b2 * b2, b8 = b4 * b4, F16b = b8 * b8;
        double b32 = F16b * F16b, b64 = b32 * b32, b128 = b64 * b64,
               b256 = b128 * b128, b512 = b256 * b256, F1kb = b512 * b512;
        double F4kb = (F1kb * F1kb) * (F1kb * F1kb);

        cf[0]  = (float)L1d;
        cf[1]  = (float)L2d;
        cf[2]  = (float)C0d;
        cf[3]  = (float)C1d;
        cf[4]  = (float)C2d;
        cf[5]  = (float)F16a;
        cf[6]  = (float)F16b;
        cf[7]  = 16.0f * log2f((float)L1d);      // float HW log2 (was fp64 sw)
        cf[8]  = 16.0f * log2f((float)L2d);
        cf[9]  = (float)F1ka;
        cf[10] = (float)F1kb;
        cf[11] = (float)(1.0 / (1.0 - F4ka));
        cf[12] = (float)(1.0 / (1.0 - F4kb));
    }
    __syncthreads();

    const float lam1 = cf[0], lam2 = cf[1];
    const float c0 = cf[2], c1 = cf[3], c2 = cf[4];
    const float f16a = cf[5], f16b = cf[6];
    const float l2a = cf[7], l2b = cf[8];
    const float f1ka = cf[9], f1kb = cf[10];
    const float ioma = cf[11], iomb = cf[12];

    // ---- local partials: r_t = sum_j lam^{15-j} s[j] (both poles) ----
    float w1 = 0.0f, w2 = 0.0f;
#pragma unroll
    for (int j = 0; j < 16; ++j) {
        w1 = fmaf(lam1, w1, s[j]);
        w2 = fmaf(lam2, w2, s[j]);
    }

    // ---- intra-wave weighted inclusive scan (combine factor lam^16) ----
    float f1 = f16a, f2 = f16b;
#pragma unroll
    for (int d = 1; d < 64; d <<= 1) {
        float o1 = __shfl_up(w1, d);
        float o2 = __shfl_up(w2, d);
        if (lane >= d) { w1 = fmaf(f1, o1, w1); w2 = fmaf(f2, o2, w2); }
        f1 *= f1; f2 *= f2;
    }
    if (lane == 63) { Tw[0][wv] = w1; Tw[1][wv] = w2; }
    __syncthreads();

    // ---- emit: only waves 0,1 (reversed positions m = 16t..16t+15 -> out[2047-m]) ----
    if (t < 128) {
        // cross-wave prefix (wave 0: none; wave 1: wave 0's total)
        float S1 = 0.0f, S2 = 0.0f;
        if (wv == 1) { S1 = Tw[0][0]; S2 = Tw[1][0]; }
        const float el1 = exp2f((float)lane * l2a);   // lam1^{16*lane}
        const float el2 = exp2f((float)lane * l2b);
        // merged inclusive value, then incoming prefix W[m0-1]
        w1 = fmaf(el1 * f16a, S1, w1);
        w2 = fmaf(el2 * f16b, S2, w2);
        float p1 = __shfl_up(w1, 1); if (lane == 0) p1 = S1;
        float p2 = __shfl_up(w2, 1); if (lane == 0) p2 = S2;

        // block totals (= W[4095]) from the 4 wave totals; periodic K
        float K1 = fmaf(fmaf(fmaf(Tw[0][0], f1ka, Tw[0][1]), f1ka, Tw[0][2]), f1ka, Tw[0][3]) * ioma;
        float K2 = fmaf(fmaf(fmaf(Tw[1][0], f1kb, Tw[1][1]), f1kb, Tw[1][2]), f1kb, Tw[1][3]) * iomb;

        // seed the replay with the periodic correction: w_c[m0-1] = p + lam^{16t} * K
        const float pw1 = el1 * (wv ? f1ka : 1.0f);   // lam1^{16t}
        const float pw2 = el2 * (wv ? f1kb : 1.0f);
        float w1r = fmaf(pw1, K1, p1);
        float w2r = fmaf(pw2, K2, p2);

        float* ob = out + (size_t)b * LSEG;
#pragma unroll
        for (int u = 0; u < 4; ++u) {
            float y0, y1, y2, y3;
            {
                const float sv = s[4 * u + 0];
                w1r = fmaf(lam1, w1r, sv); w2r = fmaf(lam2, w2r, sv);
                y0 = fmaf(c0, sv, fmaf(c2, w2r, c1 * w1r));
            }
            {
                const float sv = s[4 * u + 1];
                w1r = fmaf(lam1, w1r, sv); w2r = fmaf(lam2, w2r, sv);
                y1 = fmaf(c0, sv, fmaf(c2, w2r, c1 * w1r));
            }
            {
                const float sv = s[4 * u + 2];
                w1r = fmaf(lam1, w1r, sv); w2r = fmaf(lam2, w2r, sv);
                y2 = fmaf(c0, sv, fmaf(c2, w2r, c1 * w1r));
            }
            {
                const float sv = s[4 * u + 3];
                w1r = fmaf(lam1, w1r, sv); w2r = fmaf(lam2, w2r, sv);
                y3 = fmaf(c0, sv, fmaf(c2, w2r, c1 * w1r));
            }
            v4f o;
            o.x = y3; o.y = y2; o.z = y1; o.w = y0;   // out idx 2044-16t-4u .. +3
            *(v4f*)(ob + (2044 - 16 * t - 4 * u)) = o;
        }
    }
}

extern "C" void kernel_launch(void* const* d_in, const int* in_sizes, int n_in,
                              void* d_out, int out_size, void* d_ws, size_t ws_size,
                              hipStream_t stream) {
    const float* x     = (const float*)d_in[0];
    const float* cond  = (const float*)d_in[1];
    const float* state = (const float*)d_in[2];
    const float* a_rg  = (const float*)d_in[3];
    const float* a_r1  = (const float*)d_in[4];
    const float* a_c1  = (const float*)d_in[5];
    const float* a_c2  = (const float*)d_in[6];
    const float* c_w   = (const float*)d_in[7];
    const float* c_b   = (const float*)d_in[8];
    float* out = (float*)d_out;

    const int B = in_sizes[1];          // cond is [B,1]

    preamp_iir_kernel<<<dim3(B), dim3(256), 0, stream>>>(
        x, state, cond, a_rg, a_r1, a_c1, a_c2, c_w, c_b, out, B);
}